// Round 6
// baseline (105.758 us; speedup 1.0000x reference)
//
#include <hip/hip_runtime.h>

#define NP 64
#define NV 2562
#define KK 192         // NP*3
#define STR 200        // LDS row stride in shorts: 100 dwords %32=4 -> 2-way (free), 400B (16B-aligned)
#define NVB 32         // vertices per block (2 n-tiles)
#define GX 81          // ceil(2576/32)
#define GY 16          // 256 bs / 16 bs-per-block

typedef short bf16x8 __attribute__((ext_vector_type(8)));
typedef float f32x4  __attribute__((ext_vector_type(4)));

// RNE float->bf16
static __device__ __forceinline__ unsigned short f2bf(float x) {
    unsigned u = __float_as_uint(x);
    return (unsigned short)((u + 0x7fffu + ((u >> 16) & 1u)) >> 16);
}

// Single dispatch.
//   GEMM part (bf16, K=192): acc[i][v] = sum_{p,j} Rws[bs,p][i][j] * off[p][v][j]
//   fp32 epilogue:           out[bs,v,i] = acc + Rsum[bs][i][:].bv[v] + trans[bs][i]
__global__ __launch_bounds__(256) void fused_gemm_kernel(
    const float* __restrict__ scales,      // [256]
    const float* __restrict__ transforms,  // [256][64][6]
    const float* __restrict__ weights,     // [256][64]
    const float* __restrict__ offsets,     // [64][2562][3]
    const float* __restrict__ bverts,      // [2562][3]
    float* __restrict__ out)               // [256][2562][3]
{
    __shared__ unsigned short Alds[64][STR];   // 16 bs x 4 m-rows
    __shared__ unsigned short Blds[NVB][STR];  // 32 v-rows
    __shared__ float saux[16][12];             // per-bs fp32 Rsum[9], trans[3]

    const int t   = threadIdx.x;
    const int n0  = blockIdx.x * NVB;
    const int bs0 = blockIdx.y * 16;

    // ---- phase 0: stage B = bf16(off), K-contiguous per v-row ----
    {
        const int p  = t >> 2;          // 0..63
        const int vg = (t & 3) * 8;     // 0,8,16,24
#pragma unroll
        for (int v8 = 0; v8 < 8; ++v8) {
            const int vloc = vg + v8;
            const int v    = n0 + vloc;
            const int vc   = v < NV ? v : NV - 1;
            const float* o = offsets + ((size_t)p * NV + vc) * 3;
            Blds[vloc][p * 3 + 0] = f2bf(o[0]);
            Blds[vloc][p * 3 + 1] = f2bf(o[1]);
            Blds[vloc][p * 3 + 2] = f2bf(o[2]);
        }
    }

    // ---- phase 1: A rows (bf16 Rws) + fp32 Rsum/trans reductions ----
    {
        const int w = t >> 6;           // wave 0..3
        const int p = t & 63;           // lane = prototype
#pragma unroll
        for (int j = 0; j < 4; ++j) {
            const int bs = bs0 + w * 4 + j;
            const float sc = scales[bs];
            const float* tr = transforms + ((size_t)bs * NP + p) * 6;
            const float tx = tr[0], ty = tr[1], tz = tr[2];
            const float ax = tr[3], ay = tr[4], az = tr[5];
            const float wgt = weights[bs * NP + p];
            const float ws  = wgt * sc;

            float sx, cx, sy, cy, sz, cz;
            __sincosf(ax, &sx, &cx);
            __sincosf(ay, &sy, &cy);
            __sincosf(az, &sz, &cz);

            float v12[12];
            v12[0] = (cy * cz) * ws;
            v12[1] = (-cy * sz) * ws;
            v12[2] = (sy) * ws;
            v12[3] = (cx * sz + sx * sy * cz) * ws;
            v12[4] = (cx * cz - sx * sy * sz) * ws;
            v12[5] = (-sx * cy) * ws;
            v12[6] = (sx * sz - cx * sy * cz) * ws;
            v12[7] = (sx * cz + cx * sy * sz) * ws;
            v12[8] = (cx * cy) * ws;
            v12[9]  = wgt * tx;
            v12[10] = wgt * ty;
            v12[11] = wgt * tz;

            const int r0 = w * 16 + j * 4;
#pragma unroll
            for (int i = 0; i < 3; ++i) {
                Alds[r0 + i][p * 3 + 0] = f2bf(v12[i * 3 + 0]);
                Alds[r0 + i][p * 3 + 1] = f2bf(v12[i * 3 + 1]);
                Alds[r0 + i][p * 3 + 2] = f2bf(v12[i * 3 + 2]);
            }
            // zero pad row (m-row i=3) so stray NaNs never enter MFMA
            Alds[r0 + 3][p * 3 + 0] = 0;
            Alds[r0 + 3][p * 3 + 1] = 0;
            Alds[r0 + 3][p * 3 + 2] = 0;

            // fp32 full-wave reduction over p -> Rsum, trans
            float red[12];
#pragma unroll
            for (int k = 0; k < 12; ++k) red[k] = v12[k];
#pragma unroll
            for (int m = 1; m < 64; m <<= 1) {
#pragma unroll
                for (int k = 0; k < 12; ++k) red[k] += __shfl_xor(red[k], m);
            }
            if (p == 0) {
#pragma unroll
                for (int k = 0; k < 12; ++k) saux[w * 4 + j][k] = red[k];
            }
        }
    }
    __syncthreads();

    // ---- phase 2: MFMA, K=192 (6 steps), 2 n-tiles per wave ----
    const int w    = t >> 6;
    const int lane = t & 63;
    const int q    = lane >> 4;          // k-chunk quad / D-row group
    const int r16  = lane & 15;

    const unsigned short* ap  = &Alds[w * 16 + r16][q * 8];
    const unsigned short* bp0 = &Blds[r16][q * 8];
    const unsigned short* bp1 = &Blds[16 + r16][q * 8];

    f32x4 acc0 = {0.f, 0.f, 0.f, 0.f};
    f32x4 acc1 = {0.f, 0.f, 0.f, 0.f};
#pragma unroll
    for (int ks = 0; ks < 6; ++ks) {
        bf16x8 a  = *(const bf16x8*)(ap  + ks * 32);
        bf16x8 b0 = *(const bf16x8*)(bp0 + ks * 32);
        bf16x8 b1 = *(const bf16x8*)(bp1 + ks * 32);
        acc0 = __builtin_amdgcn_mfma_f32_16x16x32_bf16(a, b0, acc0, 0, 0, 0);
        acc1 = __builtin_amdgcn_mfma_f32_16x16x32_bf16(a, b1, acc1, 0, 0, 0);
    }

    // ---- phase 3: fp32 epilogue + direct store ----
    // lane(q,r16): D rows q*4+rg (rg=0..2 -> i), col r16 -> v. bs = bs0+w*4+q.
    const int bsl = w * 4 + q;
    float R[12];
#pragma unroll
    for (int k = 0; k < 12; ++k) R[k] = saux[bsl][k];  // broadcast per 16-lane group

    const int bs = bs0 + bsl;
    {
        const int v = n0 + r16;
        if (v < NV) {
            const float bx = bverts[v * 3 + 0];
            const float by = bverts[v * 3 + 1];
            const float bz = bverts[v * 3 + 2];
            float* po = out + ((size_t)bs * NV + v) * 3;
            po[0] = acc0[0] + R[0] * bx + R[1] * by + R[2] * bz + R[9];
            po[1] = acc0[1] + R[3] * bx + R[4] * by + R[5] * bz + R[10];
            po[2] = acc0[2] + R[6] * bx + R[7] * by + R[8] * bz + R[11];
        }
        const int v1 = n0 + 16 + r16;
        if (v1 < NV) {
            const float bx = bverts[v1 * 3 + 0];
            const float by = bverts[v1 * 3 + 1];
            const float bz = bverts[v1 * 3 + 2];
            float* po = out + ((size_t)bs * NV + v1) * 3;
            po[0] = acc1[0] + R[0] * bx + R[1] * by + R[2] * bz + R[9];
            po[1] = acc1[1] + R[3] * bx + R[4] * by + R[5] * bz + R[10];
            po[2] = acc1[2] + R[6] * bx + R[7] * by + R[8] * bz + R[11];
        }
    }
}

extern "C" void kernel_launch(void* const* d_in, const int* in_sizes, int n_in,
                              void* d_out, int out_size, void* d_ws, size_t ws_size,
                              hipStream_t stream) {
    const float* scales     = (const float*)d_in[0];
    const float* transforms = (const float*)d_in[1];
    const float* weights    = (const float*)d_in[2];
    const float* offsets    = (const float*)d_in[3];
    const float* bverts     = (const float*)d_in[4];
    float* out = (float*)d_out;

    fused_gemm_kernel<<<dim3(GX, GY), dim3(256), 0, stream>>>(
        scales, transforms, weights, offsets, bverts, out);
}

// Round 7
// 82.458 us; speedup vs baseline: 1.2826x; 1.2826x over previous
//
#include <hip/hip_runtime.h>

#define NP 64
#define NV 2562
#define KK 192          // NP*3
#define NROWS_B 2592    // 81*32 padded Bt rows
#define GXN 81          // n-blocks (32 v each)
#define GYM 8           // m-blocks (8 m-tiles each)

typedef short bf16x8 __attribute__((ext_vector_type(8)));
typedef float f32x4  __attribute__((ext_vector_type(4)));

// RNE float->bf16
static __device__ __forceinline__ unsigned short f2bf(float x) {
    unsigned u = __float_as_uint(x);
    return (unsigned short)((u + 0x7fffu + ((u >> 16) & 1u)) >> 16);
}

// ---------------- prep: one dispatch, two roles by blockIdx ----------------
// blocks [0,256):  role A: bs = blockIdx.x, lane = p.
//   A[bs*4+i][3p+j] = bf16(Rws[i][j]);  aux[bs][0..8]=fp32 Rsum, [9..11]=trans
// blocks [256,297): role B: v = (blockIdx.x-256)*64 + lane.
//   Bt[v][3p+j] = bf16(off[p][v][j]); rows v in [NV, 2592) zero-filled.
__global__ __launch_bounds__(64) void prep_kernel(
    const float* __restrict__ scales,      // [256]
    const float* __restrict__ transforms,  // [256][64][6]
    const float* __restrict__ weights,     // [256][64]
    const float* __restrict__ offsets,     // [64][2562][3]
    unsigned short* __restrict__ A,        // [1024][192]
    unsigned short* __restrict__ Bt,       // [2592][192]
    float* __restrict__ aux)               // [256][12]
{
    const int blk = blockIdx.x;
    const int t   = threadIdx.x;

    if (blk < 256) {
        // ---------- role A ----------
        const int bs = blk;
        const int p  = t;
        const float* tr = transforms + ((size_t)bs * NP + p) * 6;
        const float tx = tr[0], ty = tr[1], tz = tr[2];
        const float ax = tr[3], ay = tr[4], az = tr[5];
        const float wgt = weights[bs * NP + p];
        const float ws  = wgt * scales[bs];

        float sx, cx, sy, cy, sz, cz;
        __sincosf(ax, &sx, &cx);
        __sincosf(ay, &sy, &cy);
        __sincosf(az, &sz, &cz);

        float v12[12];
        v12[0] = (cy * cz) * ws;
        v12[1] = (-cy * sz) * ws;
        v12[2] = (sy) * ws;
        v12[3] = (cx * sz + sx * sy * cz) * ws;
        v12[4] = (cx * cz - sx * sy * sz) * ws;
        v12[5] = (-sx * cy) * ws;
        v12[6] = (sx * sz - cx * sy * cz) * ws;
        v12[7] = (sx * cz + cx * sy * sz) * ws;
        v12[8] = (cx * cy) * ws;
        v12[9]  = wgt * tx;
        v12[10] = wgt * ty;
        v12[11] = wgt * tz;

#pragma unroll
        for (int i = 0; i < 3; ++i) {
            unsigned short* row = A + ((size_t)(bs * 4 + i)) * KK + p * 3;
            row[0] = f2bf(v12[i * 3 + 0]);
            row[1] = f2bf(v12[i * 3 + 1]);
            row[2] = f2bf(v12[i * 3 + 2]);
        }
        // zero pad m-row i=3 (keep MFMA inputs clean)
        {
            unsigned short* row = A + ((size_t)(bs * 4 + 3)) * KK + p * 3;
            row[0] = 0; row[1] = 0; row[2] = 0;
        }

        // fp32 full-wave reduction over p
        float red[12];
#pragma unroll
        for (int k = 0; k < 12; ++k) red[k] = v12[k];
#pragma unroll
        for (int m = 1; m < 64; m <<= 1) {
#pragma unroll
            for (int k = 0; k < 12; ++k) red[k] += __shfl_xor(red[k], m);
        }
        if (p == 0) {
#pragma unroll
            for (int k = 0; k < 12; ++k) aux[bs * 12 + k] = red[k];
        }
    } else {
        // ---------- role B: transpose offsets -> bf16 Bt ----------
        const int v = (blk - 256) * 64 + t;
        if (v >= NROWS_B) return;
        const bool live = (v < NV);

        // 8 chunks of 8 p: buffer 24 shorts, store as 3 dwordx4 (48B)
#pragma unroll 1
        for (int pc = 0; pc < 8; ++pc) {
            unsigned short tmp[24];
#pragma unroll
            for (int pi = 0; pi < 8; ++pi) {
                const int p = pc * 8 + pi;
                float o0 = 0.f, o1 = 0.f, o2 = 0.f;
                if (live) {
                    const float* o = offsets + ((size_t)p * NV + v) * 3;
                    o0 = o[0]; o1 = o[1]; o2 = o[2];
                }
                tmp[pi * 3 + 0] = f2bf(o0);
                tmp[pi * 3 + 1] = f2bf(o1);
                tmp[pi * 3 + 2] = f2bf(o2);
            }
            uint4* dst = (uint4*)(Bt + (size_t)v * KK + pc * 24);
            *dst       = *(const uint4*)(tmp);
            *(dst + 1) = *(const uint4*)(tmp + 8);
            *(dst + 2) = *(const uint4*)(tmp + 16);
        }
    }
}

// ---------------- gemm: LDS-free, 2x2 tiles per wave -----------------------
// grid (81, 8) x 256 threads. Wave w: m-tiles {by*8+2w, +1}, n-tiles {bx*2, +1}.
// Fragment loads: lane(q,r16) reads row r16 (of 16), bytes [q*16 .. +16) of the
// 64B k-slab -> one b128 instr = 16 rows x 64B contiguous = 16 cache lines.
__global__ __launch_bounds__(256) void gemm_kernel(
    const unsigned short* __restrict__ A,   // [1024][192]
    const unsigned short* __restrict__ Bt,  // [2592][192]
    const float* __restrict__ aux,          // [256][12]
    const float* __restrict__ bverts,       // [2562][3]
    float* __restrict__ out)                // [256][2562][3]
{
    const int t    = threadIdx.x;
    const int w    = t >> 6;
    const int lane = t & 63;
    const int q    = lane >> 4;
    const int r16  = lane & 15;

    const int np0 = blockIdx.x * 32;            // n base (2 tiles of 16)
    const int mt0 = blockIdx.y * 8 + w * 2;     // first m-tile of this wave

    const unsigned short* ap0 = A  + ((size_t)(mt0 * 16) + r16) * KK + q * 8;
    const unsigned short* ap1 = ap0 + 16 * KK;
    const unsigned short* bp0 = Bt + ((size_t)np0 + r16) * KK + q * 8;
    const unsigned short* bp1 = bp0 + 16 * KK;

    f32x4 acc00 = {0,0,0,0}, acc01 = {0,0,0,0};
    f32x4 acc10 = {0,0,0,0}, acc11 = {0,0,0,0};

#pragma unroll
    for (int ks = 0; ks < 6; ++ks) {
        bf16x8 a0 = *(const bf16x8*)(ap0 + ks * 32);
        bf16x8 a1 = *(const bf16x8*)(ap1 + ks * 32);
        bf16x8 b0 = *(const bf16x8*)(bp0 + ks * 32);
        bf16x8 b1 = *(const bf16x8*)(bp1 + ks * 32);
        acc00 = __builtin_amdgcn_mfma_f32_16x16x32_bf16(a0, b0, acc00, 0, 0, 0);
        acc01 = __builtin_amdgcn_mfma_f32_16x16x32_bf16(a0, b1, acc01, 0, 0, 0);
        acc10 = __builtin_amdgcn_mfma_f32_16x16x32_bf16(a1, b0, acc10, 0, 0, 0);
        acc11 = __builtin_amdgcn_mfma_f32_16x16x32_bf16(a1, b1, acc11, 0, 0, 0);
    }

    // fp32 epilogue, direct acc-layout stores.
    // D layout: col=r16 -> v, row=q*4+rg -> m-local; m-tile = 4 bs x 4 i,
    // so bs = mt*4 + q, i = rg (rg=3 is the pad row, dropped).
    const int v0 = np0 + r16;
    const int v1 = v0 + 16;
    float b0x = 0, b0y = 0, b0z = 0, b1x = 0, b1y = 0, b1z = 0;
    if (v0 < NV) { const float* b = bverts + (size_t)v0 * 3; b0x = b[0]; b0y = b[1]; b0z = b[2]; }
    if (v1 < NV) { const float* b = bverts + (size_t)v1 * 3; b1x = b[0]; b1y = b[1]; b1z = b[2]; }

#pragma unroll
    for (int mi = 0; mi < 2; ++mi) {
        const int bs = (mt0 + mi) * 4 + q;
        const float4 R0 = *(const float4*)(aux + bs * 12);      // Rsum[0..3]
        const float4 R1 = *(const float4*)(aux + bs * 12 + 4);  // Rsum[4..7]
        const float4 R2 = *(const float4*)(aux + bs * 12 + 8);  // Rsum[8], t[0..2]
        const f32x4 a0 = mi ? acc10 : acc00;
        const f32x4 a1 = mi ? acc11 : acc01;

        if (v0 < NV) {
            float* po = out + ((size_t)bs * NV + v0) * 3;
            po[0] = a0[0] + R0.x * b0x + R0.y * b0y + R0.z * b0z + R2.y;
            po[1] = a0[1] + R0.w * b0x + R1.x * b0y + R1.y * b0z + R2.z;
            po[2] = a0[2] + R1.z * b0x + R1.w * b0y + R2.x * b0z + R2.w;
        }
        if (v1 < NV) {
            float* po = out + ((size_t)bs * NV + v1) * 3;
            po[0] = a1[0] + R0.x * b1x + R0.y * b1y + R0.z * b1z + R2.y;
            po[1] = a1[1] + R0.w * b1x + R1.x * b1y + R1.y * b1z + R2.z;
            po[2] = a1[2] + R1.z * b1x + R1.w * b1y + R2.x * b1z + R2.w;
        }
    }
}

extern "C" void kernel_launch(void* const* d_in, const int* in_sizes, int n_in,
                              void* d_out, int out_size, void* d_ws, size_t ws_size,
                              hipStream_t stream) {
    const float* scales     = (const float*)d_in[0];
    const float* transforms = (const float*)d_in[1];
    const float* weights    = (const float*)d_in[2];
    const float* offsets    = (const float*)d_in[3];
    const float* bverts     = (const float*)d_in[4];
    float* out = (float*)d_out;

    unsigned short* A  = (unsigned short*)d_ws;                 // 1024*192*2   = 393216 B
    unsigned short* Bt = A + (size_t)1024 * KK;                 // 2592*192*2   = 995328 B
    float* aux = (float*)(Bt + (size_t)NROWS_B * KK);           // 256*12*4     (16B-aligned)

    prep_kernel<<<dim3(256 + (NROWS_B + 63) / 64), dim3(64), 0, stream>>>(
        scales, transforms, weights, offsets, A, Bt, aux);

    gemm_kernel<<<dim3(GXN, GYM), dim3(256), 0, stream>>>(A, Bt, aux, bverts, out);
}

// Round 8
// 78.228 us; speedup vs baseline: 1.3519x; 1.0541x over previous
//
#include <hip/hip_runtime.h>

#define NP 64
#define NV 2562
#define KK 192          // NP*3
#define NROWS_B 2592    // 81*32 padded Bt rows
#define GXN 81          // n-blocks (32 v each)
#define GYM 8           // m-blocks (8 m-tiles each)

typedef short bf16x8 __attribute__((ext_vector_type(8)));
typedef float f32x4  __attribute__((ext_vector_type(4)));

// RNE float->bf16
static __device__ __forceinline__ unsigned short f2bf(float x) {
    unsigned u = __float_as_uint(x);
    return (unsigned short)((u + 0x7fffu + ((u >> 16) & 1u)) >> 16);
}

// ---------------- prep: one dispatch, two roles by blockIdx ----------------
// blocks [0,64):    role A: 4 waves, wave handles bs = blk*4+wave, lane = p.
//   A[bs*4+i][3p+j] = bf16(Rws[i][j]); aux[bs][0..8]=fp32 Rsum, [9..11]=trans
// blocks [64,145):  role B: thread=(vloc,pc): v=(blk-64)*32+vloc, pc=0..7.
//   Bt[v][pc*24 + pi*3 + j] = bf16(off[pc*8+pi][v][j]); rows >= NV zeroed.
__global__ __launch_bounds__(256) void prep_kernel(
    const float* __restrict__ scales,      // [256]
    const float* __restrict__ transforms,  // [256][64][6]
    const float* __restrict__ weights,     // [256][64]
    const float* __restrict__ offsets,     // [64][2562][3]
    unsigned short* __restrict__ A,        // [1024][192]
    unsigned short* __restrict__ Bt,       // [2592][192]
    float* __restrict__ aux)               // [256][12]
{
    const int blk = blockIdx.x;
    const int t   = threadIdx.x;

    if (blk < 64) {
        // ---------- role A ----------
        const int wave = t >> 6;
        const int p    = t & 63;
        const int bs   = blk * 4 + wave;

        const float* tr = transforms + ((size_t)bs * NP + p) * 6;
        const float tx = tr[0], ty = tr[1], tz = tr[2];
        const float ax = tr[3], ay = tr[4], az = tr[5];
        const float wgt = weights[bs * NP + p];
        const float ws  = wgt * scales[bs];

        float sx, cx, sy, cy, sz, cz;
        __sincosf(ax, &sx, &cx);
        __sincosf(ay, &sy, &cy);
        __sincosf(az, &sz, &cz);

        float v12[12];
        v12[0] = (cy * cz) * ws;
        v12[1] = (-cy * sz) * ws;
        v12[2] = (sy) * ws;
        v12[3] = (cx * sz + sx * sy * cz) * ws;
        v12[4] = (cx * cz - sx * sy * sz) * ws;
        v12[5] = (-sx * cy) * ws;
        v12[6] = (sx * sz - cx * sy * cz) * ws;
        v12[7] = (sx * cz + cx * sy * sz) * ws;
        v12[8] = (cx * cy) * ws;
        v12[9]  = wgt * tx;
        v12[10] = wgt * ty;
        v12[11] = wgt * tz;

#pragma unroll
        for (int i = 0; i < 3; ++i) {
            unsigned short* row = A + ((size_t)(bs * 4 + i)) * KK + p * 3;
            row[0] = f2bf(v12[i * 3 + 0]);
            row[1] = f2bf(v12[i * 3 + 1]);
            row[2] = f2bf(v12[i * 3 + 2]);
        }
        {   // zero pad m-row i=3
            unsigned short* row = A + ((size_t)(bs * 4 + 3)) * KK + p * 3;
            row[0] = 0; row[1] = 0; row[2] = 0;
        }

        // fp32 full-wave reduction over p -> Rsum, trans
        float red[12];
#pragma unroll
        for (int k = 0; k < 12; ++k) red[k] = v12[k];
#pragma unroll
        for (int m = 1; m < 64; m <<= 1) {
#pragma unroll
            for (int k = 0; k < 12; ++k) red[k] += __shfl_xor(red[k], m);
        }
        if (p == 0) {
#pragma unroll
            for (int k = 0; k < 12; ++k) aux[bs * 12 + k] = red[k];
        }
    } else {
        // ---------- role B: transpose offsets -> bf16 Bt ----------
        const int vloc = t >> 3;               // 0..31
        const int pc   = t & 7;                // 0..7
        const int v    = (blk - 64) * 32 + vloc;
        const bool live = (v < NV);

        unsigned short tmp[24];
#pragma unroll
        for (int pi = 0; pi < 8; ++pi) {
            const int p = pc * 8 + pi;
            float o0 = 0.f, o1 = 0.f, o2 = 0.f;
            if (live) {
                const float* o = offsets + ((size_t)p * NV + v) * 3;
                o0 = o[0]; o1 = o[1]; o2 = o[2];
            }
            tmp[pi * 3 + 0] = f2bf(o0);
            tmp[pi * 3 + 1] = f2bf(o1);
            tmp[pi * 3 + 2] = f2bf(o2);
        }
        uint4* dst = (uint4*)(Bt + (size_t)v * KK + pc * 24);  // pc*48B: 16B-aligned
        dst[0] = *(const uint4*)(tmp);
        dst[1] = *(const uint4*)(tmp + 8);
        dst[2] = *(const uint4*)(tmp + 16);
    }
}

// ---------------- gemm: LDS-free, 2x2 tiles per wave (unchanged, R7) -------
__global__ __launch_bounds__(256) void gemm_kernel(
    const unsigned short* __restrict__ A,   // [1024][192]
    const unsigned short* __restrict__ Bt,  // [2592][192]
    const float* __restrict__ aux,          // [256][12]
    const float* __restrict__ bverts,       // [2562][3]
    float* __restrict__ out)                // [256][2562][3]
{
    const int t    = threadIdx.x;
    const int w    = t >> 6;
    const int lane = t & 63;
    const int q    = lane >> 4;
    const int r16  = lane & 15;

    const int np0 = blockIdx.x * 32;            // n base (2 tiles of 16)
    const int mt0 = blockIdx.y * 8 + w * 2;     // first m-tile of this wave

    const unsigned short* ap0 = A  + ((size_t)(mt0 * 16) + r16) * KK + q * 8;
    const unsigned short* ap1 = ap0 + 16 * KK;
    const unsigned short* bp0 = Bt + ((size_t)np0 + r16) * KK + q * 8;
    const unsigned short* bp1 = bp0 + 16 * KK;

    f32x4 acc00 = {0,0,0,0}, acc01 = {0,0,0,0};
    f32x4 acc10 = {0,0,0,0}, acc11 = {0,0,0,0};

#pragma unroll
    for (int ks = 0; ks < 6; ++ks) {
        bf16x8 a0 = *(const bf16x8*)(ap0 + ks * 32);
        bf16x8 a1 = *(const bf16x8*)(ap1 + ks * 32);
        bf16x8 b0 = *(const bf16x8*)(bp0 + ks * 32);
        bf16x8 b1 = *(const bf16x8*)(bp1 + ks * 32);
        acc00 = __builtin_amdgcn_mfma_f32_16x16x32_bf16(a0, b0, acc00, 0, 0, 0);
        acc01 = __builtin_amdgcn_mfma_f32_16x16x32_bf16(a0, b1, acc01, 0, 0, 0);
        acc10 = __builtin_amdgcn_mfma_f32_16x16x32_bf16(a1, b0, acc10, 0, 0, 0);
        acc11 = __builtin_amdgcn_mfma_f32_16x16x32_bf16(a1, b1, acc11, 0, 0, 0);
    }

    // fp32 epilogue, direct acc-layout stores.
    const int v0 = np0 + r16;
    const int v1 = v0 + 16;
    float b0x = 0, b0y = 0, b0z = 0, b1x = 0, b1y = 0, b1z = 0;
    if (v0 < NV) { const float* b = bverts + (size_t)v0 * 3; b0x = b[0]; b0y = b[1]; b0z = b[2]; }
    if (v1 < NV) { const float* b = bverts + (size_t)v1 * 3; b1x = b[0]; b1y = b[1]; b1z = b[2]; }

#pragma unroll
    for (int mi = 0; mi < 2; ++mi) {
        const int bs = (mt0 + mi) * 4 + q;
        const float4 R0 = *(const float4*)(aux + bs * 12);
        const float4 R1 = *(const float4*)(aux + bs * 12 + 4);
        const float4 R2 = *(const float4*)(aux + bs * 12 + 8);
        const f32x4 a0 = mi ? acc10 : acc00;
        const f32x4 a1 = mi ? acc11 : acc01;

        if (v0 < NV) {
            float* po = out + ((size_t)bs * NV + v0) * 3;
            po[0] = a0[0] + R0.x * b0x + R0.y * b0y + R0.z * b0z + R2.y;
            po[1] = a0[1] + R0.w * b0x + R1.x * b0y + R1.y * b0z + R2.z;
            po[2] = a0[2] + R1.z * b0x + R1.w * b0y + R2.x * b0z + R2.w;
        }
        if (v1 < NV) {
            float* po = out + ((size_t)bs * NV + v1) * 3;
            po[0] = a1[0] + R0.x * b1x + R0.y * b1y + R0.z * b1z + R2.y;
            po[1] = a1[1] + R0.w * b1x + R1.x * b1y + R1.y * b1z + R2.z;
            po[2] = a1[2] + R1.z * b1x + R1.w * b1y + R2.x * b1z + R2.w;
        }
    }
}

extern "C" void kernel_launch(void* const* d_in, const int* in_sizes, int n_in,
                              void* d_out, int out_size, void* d_ws, size_t ws_size,
                              hipStream_t stream) {
    const float* scales     = (const float*)d_in[0];
    const float* transforms = (const float*)d_in[1];
    const float* weights    = (const float*)d_in[2];
    const float* offsets    = (const float*)d_in[3];
    const float* bverts     = (const float*)d_in[4];
    float* out = (float*)d_out;

    unsigned short* A  = (unsigned short*)d_ws;                 // 1024*192*2   = 393216 B
    unsigned short* Bt = A + (size_t)1024 * KK;                 // 2592*192*2   = 995328 B
    float* aux = (float*)(Bt + (size_t)NROWS_B * KK);           // 256*12*4     (16B-aligned)

    prep_kernel<<<dim3(64 + GXN), dim3(256), 0, stream>>>(
        scales, transforms, weights, offsets, A, Bt, aux);

    gemm_kernel<<<dim3(GXN, GYM), dim3(256), 0, stream>>>(A, Bt, aux, bverts, out);
}